// Round 15
// baseline (217.721 us; speedup 1.0000x reference)
//
#include <hip/hip_runtime.h>
#include <stdint.h>

// Problem constants
#define BB 4
#define LL 2048
#define DD 1024

typedef __attribute__((ext_vector_type(4))) float f32x4;
typedef __attribute__((ext_vector_type(8))) _Float16 f16x8;
typedef __attribute__((ext_vector_type(4))) unsigned short u16x4;
typedef __attribute__((ext_vector_type(8))) unsigned short u16x8;
typedef unsigned short u16;

// ---------- fp16 helpers ----------
__device__ __forceinline__ u16 f2h(float x){
  return __builtin_bit_cast(u16, (_Float16)x);
}
__device__ __forceinline__ float h2f(u16 h){
  return (float)__builtin_bit_cast(_Float16, h);
}

// ---------- async global->LDS staging (16B/lane) ----------
__device__ __forceinline__ void gload16(const u16* g, u16* l){
  __builtin_amdgcn_global_load_lds((const __attribute__((address_space(1))) unsigned*)g,
                                   (__attribute__((address_space(3))) unsigned*)l,
                                   16, 0, 0);
}

// XCD-aware chunked block swizzle (requires nwg % 8 == 0; all our grids comply)
__device__ __forceinline__ int xcd_swz(int bx, int nwg){
  return (bx & 7) * (nwg >> 3) + (bx >> 3);
}

// stage a [128][64] fp16 tile, 8 waves, XOR-swizzled source, linear LDS dest
__device__ __forceinline__ void stage_tile8(u16* lds, const u16* src, int ld, int wave, int lane){
  const int r0 = lane >> 3;
  const int cs = (((lane & 7) ^ r0) << 3);
  #pragma unroll
  for (int j = 0; j < 2; ++j){
    const int rb = wave*16 + j*8;
    gload16(src + (size_t)(rb + r0)*ld + cs, lds + rb*64);
  }
}

// fat-kernel staging (4 waves / 256 threads): A [256][64], B [128][64]
__device__ __forceinline__ void stage_fatA(u16* lds, const u16* src, int ld, int wave, int lane){
  const int r0 = lane >> 3;
  const int cs = (((lane & 7) ^ r0) << 3);
  #pragma unroll
  for (int j = 0; j < 8; ++j){
    const int rb = wave*64 + j*8;
    gload16(src + (size_t)(rb + r0)*ld + cs, lds + rb*64);
  }
}
__device__ __forceinline__ void stage_fatB(u16* lds, const u16* src, int ld, int wave, int lane){
  const int r0 = lane >> 3;
  const int cs = (((lane & 7) ^ r0) << 3);
  #pragma unroll
  for (int j = 0; j < 4; ++j){
    const int rb = wave*32 + j*8;
    gload16(src + (size_t)(rb + r0)*ld + cs, lds + rb*64);
  }
}

// swizzled fragment read: logical (row, ko) lives at phys col ko ^ ((row&7)<<3)
__device__ __forceinline__ f16x8 frag_ld(const u16* t, int row, int ko){
  return __builtin_bit_cast(f16x8,
    *reinterpret_cast<const f32x4*>(t + row*64 + (ko ^ ((row & 7) << 3))));
}

// ---------- kernel: all input casts in one launch ----------
// z<4: f2 batch z -> f2f (cast) + f2T (cast+transpose).
// z==4: W1 -> w1f (cast) + w1T (cast+transpose), 1024x1024 (guard l0).
// z==5: grid-stride flat cast of f1 and W2.
__global__ void cast_all_k(const float* __restrict__ f2, u16* __restrict__ f2f,
                           u16* __restrict__ f2T,
                           const float* __restrict__ W1, u16* __restrict__ w1f,
                           u16* __restrict__ w1T,
                           const float* __restrict__ f1, u16* __restrict__ f1f,
                           const float* __restrict__ W2, u16* __restrict__ w2f){
  __shared__ u16 t[32][33];
  const int z = blockIdx.z;
  if (z < 4 || z == 4){
    const float* src; u16* d1; u16* d2; int nrow, ldT;
    if (z < 4){ src = f2 + (size_t)z*LL*DD; d1 = f2f + (size_t)z*LL*DD;
                d2 = f2T + (size_t)z*DD*LL; nrow = LL; ldT = LL; }
    else      { src = W1; d1 = w1f; d2 = w1T; nrow = DD; ldT = DD; }
    const int d0 = blockIdx.x*32, l0 = blockIdx.y*32;
    if (l0 >= nrow) return;
    const int x = threadIdx.x;
    for (int j = threadIdx.y; j < 32; j += 8){
      u16 h = f2h(src[(size_t)(l0+j)*DD + d0 + x]);
      d1[(size_t)(l0+j)*DD + d0 + x] = h;
      t[j][x] = h;
    }
    __syncthreads();
    for (int j = threadIdx.y; j < 32; j += 8)
      d2[(size_t)(d0+j)*ldT + l0 + x] = t[x][j];
  } else {
    const int n1 = (BB*LL*DD)/4, nw = (DD*DD)/4;
    const int ntot = n1 + nw;
    const int base = (blockIdx.y*32 + blockIdx.x)*256 + threadIdx.y*32 + threadIdx.x;
    const int stride = 2048*256;
    for (int i = base; i < ntot; i += stride){
      const float* s; u16* d; int k;
      if (i < n1){ s = f1; d = f1f; k = i; }
      else { s = W2; d = w2f; k = i - n1; }
      f32x4 v = reinterpret_cast<const f32x4*>(s)[k];
      u16x4 h;
      #pragma unroll
      for (int j = 0; j < 4; ++j) h[j] = f2h(v[j]);
      reinterpret_cast<u16x4*>(d)[k] = h;
    }
  }
}

// ---------- kernel: bz2[d] = b2[d] + sum_e W2[d][e]*b1[e]  (f32, wave per d) ----------
__global__ __launch_bounds__(512) void bz2_k(const float* __restrict__ W2,
                                             const float* __restrict__ b1,
                                             const float* __restrict__ b2,
                                             float* __restrict__ bz2){
  const int wave = threadIdx.x >> 6, lane = threadIdx.x & 63;
  const int d = blockIdx.x*8 + wave;
  float s = 0.f;
  #pragma unroll
  for (int k = 0; k < 16; ++k){
    const int e = lane + (k << 6);
    s += W2[(size_t)d*DD + e] * b1[e];
  }
  #pragma unroll
  for (int o = 32; o; o >>= 1) s += __shfl_xor(s, o, 64);
  if (lane == 0) bz2[d] = b2[d] + s;
}

// ---------- kernel: W12 = W2 @ W1 fp16 (A=w2f [d][e], B=w1T [k][e]), 128-tile ----------
__global__ __launch_bounds__(512,4) void w12_k(const u16* __restrict__ A_g,
                                               const u16* __restrict__ B_g,
                                               u16* __restrict__ Oh){
  __shared__ __align__(16) u16 As[128*64];
  __shared__ __align__(16) u16 Bs[128*64];
  const int bx = xcd_swz(blockIdx.x, gridDim.x);
  const int bm = bx >> 3, bn = bx & 7;
  const int tid = threadIdx.x, wave = tid>>6, lane = tid&63;
  const int wr = wave>>2, wc = wave&3;
  const u16* Ab = A_g + (size_t)(bm*128)*DD;
  const u16* Bb = B_g + (size_t)(bn*128)*DD;
  f32x4 acc[4][2];
  #pragma unroll
  for (int i=0;i<4;i++)
    #pragma unroll
    for (int j=0;j<2;j++) acc[i][j] = (f32x4){0.f,0.f,0.f,0.f};
  for (int k0 = 0; k0 < DD; k0 += 64){
    __syncthreads();
    stage_tile8(As, Ab + k0, DD, wave, lane);
    stage_tile8(Bs, Bb + k0, DD, wave, lane);
    __syncthreads();
    #pragma unroll
    for (int kk=0;kk<2;kk++){
      const int ko = kk*32 + ((lane>>4)<<3);
      f16x8 a[4], bb[2];
      #pragma unroll
      for (int mi=0;mi<4;mi++) a[mi]  = frag_ld(As, wr*64 + mi*16 + (lane&15), ko);
      #pragma unroll
      for (int ni=0;ni<2;ni++) bb[ni] = frag_ld(Bs, wc*32 + ni*16 + (lane&15), ko);
      #pragma unroll
      for (int mi=0;mi<4;mi++)
        #pragma unroll
        for (int ni=0;ni<2;ni++)
          acc[mi][ni] = __builtin_amdgcn_mfma_f32_16x16x32_f16(a[mi], bb[ni], acc[mi][ni], 0,0,0);
    }
  }
  #pragma unroll
  for (int mi=0;mi<4;mi++)
    #pragma unroll
    for (int ni=0;ni<2;ni++){
      const int r = bm*128 + wr*64 + mi*16 + ((lane>>4)<<2);
      const int c = bn*128 + wc*32 + ni*16 + (lane&15);
      #pragma unroll
      for (int j=0;j<4;j++)
        Oh[(size_t)(r+j)*DD + c] = f2h(acc[mi][ni][j]);
    }
}

// ---------- kernel: fused t1 + Z. A=f1f; B1=w1f -> t1f (+b1, bit-identical to old
// gemm_t1_k path); B2=w12f -> ZT (transposed via LDS, coalesced d-major write) ----------
__global__ __launch_bounds__(512,4) void t1z_k(const u16* __restrict__ f1f,
                                               const u16* __restrict__ w1f,
                                               const u16* __restrict__ w12f,
                                               const float* __restrict__ b1,
                                               u16* __restrict__ t1f,
                                               u16* __restrict__ ZT){
  __shared__ __align__(16) u16 SH[3*128*64];       // As | B1s | B2s ; T aliases after
  u16* As  = SH;
  u16* B1s = SH + 8192;
  u16* B2s = SH + 16384;
  const int bx = xcd_swz(blockIdx.x, gridDim.x);
  const int bm = bx >> 3, bn = bx & 7;
  const int tid = threadIdx.x, wave = tid>>6, lane = tid&63;
  const int wr = wave>>2, wc = wave&3;
  const u16* Ab  = f1f  + (size_t)(bm*128)*DD;
  const u16* B1b = w1f  + (size_t)(bn*128)*DD;
  const u16* B2b = w12f + (size_t)(bn*128)*DD;
  f32x4 acc1[4][2], acc2[4][2];
  #pragma unroll
  for (int i=0;i<4;i++)
    #pragma unroll
    for (int j=0;j<2;j++){ acc1[i][j] = (f32x4){0.f,0.f,0.f,0.f}; acc2[i][j] = acc1[i][j]; }

  for (int k0 = 0; k0 < DD; k0 += 64){
    __syncthreads();
    stage_tile8(As,  Ab  + k0, DD, wave, lane);
    stage_tile8(B1s, B1b + k0, DD, wave, lane);
    stage_tile8(B2s, B2b + k0, DD, wave, lane);
    __syncthreads();
    #pragma unroll
    for (int kk=0;kk<2;kk++){
      const int ko = kk*32 + ((lane>>4)<<3);
      f16x8 a[4], b1v[2], b2v[2];
      #pragma unroll
      for (int mi=0;mi<4;mi++) a[mi]  = frag_ld(As, wr*64 + mi*16 + (lane&15), ko);
      #pragma unroll
      for (int ni=0;ni<2;ni++){
        b1v[ni] = frag_ld(B1s, wc*32 + ni*16 + (lane&15), ko);
        b2v[ni] = frag_ld(B2s, wc*32 + ni*16 + (lane&15), ko);
      }
      #pragma unroll
      for (int mi=0;mi<4;mi++)
        #pragma unroll
        for (int ni=0;ni<2;ni++){
          acc1[mi][ni] = __builtin_amdgcn_mfma_f32_16x16x32_f16(a[mi], b1v[ni], acc1[mi][ni], 0,0,0);
          acc2[mi][ni] = __builtin_amdgcn_mfma_f32_16x16x32_f16(a[mi], b2v[ni], acc2[mi][ni], 0,0,0);
        }
    }
  }
  // epilogue 1: t1f = acc1 + b1
  #pragma unroll
  for (int mi=0;mi<4;mi++)
    #pragma unroll
    for (int ni=0;ni<2;ni++){
      const int r = bm*128 + wr*64 + mi*16 + ((lane>>4)<<2);
      const int c = bn*128 + wc*32 + ni*16 + (lane&15);
      const float bv = b1[c];
      #pragma unroll
      for (int j=0;j<4;j++)
        t1f[(size_t)(r+j)*DD + c] = f2h(acc1[mi][ni][j] + bv);
    }
  // epilogue 2: ZT via LDS transpose staging (T aliases SH)
  __syncthreads();
  u16* T = SH;                                  // [128][132]
  #pragma unroll
  for (int mi=0;mi<4;mi++)
    #pragma unroll
    for (int ni=0;ni<2;ni++){
      const int r = wr*64 + mi*16 + ((lane>>4)<<2);
      const int c = wc*32 + ni*16 + (lane&15);
      #pragma unroll
      for (int j=0;j<4;j++)
        T[(r+j)*132 + c] = f2h(acc2[mi][ni][j]);
    }
  __syncthreads();
  const int b2i = bm >> 4;
  const int mb  = (bm*128) & 2047;
  const int d   = tid >> 2, m0 = (tid & 3) << 5;
  u16* dst = ZT + ((size_t)b2i*DD + bn*128 + d)*LL + mb + m0;
  #pragma unroll
  for (int g = 0; g < 4; ++g){
    u16x8 v;
    #pragma unroll
    for (int e = 0; e < 8; ++e) v[e] = T[(m0 + g*8 + e)*132 + d];
    *reinterpret_cast<u16x8*>(dst + g*8) = v;
  }
}

// ---------- kernel: row softmax fp16 -> fp16 in place ----------
__global__ __launch_bounds__(256) void softmax_k(u16* __restrict__ sim){
  const int row = blockIdx.x;
  u16* p = sim + (size_t)row * LL;
  const int tid = threadIdx.x, wave = tid>>6, lane = tid&63;
  u16x8 v = reinterpret_cast<const u16x8*>(p)[tid];
  float x[8];
  #pragma unroll
  for (int j=0;j<8;j++) x[j] = h2f(v[j]);
  float mx = fmaxf(fmaxf(fmaxf(x[0],x[1]), fmaxf(x[2],x[3])),
                   fmaxf(fmaxf(x[4],x[5]), fmaxf(x[6],x[7])));
  #pragma unroll
  for (int o = 32; o; o >>= 1) mx = fmaxf(mx, __shfl_xor(mx, o, 64));
  __shared__ float red[8];
  if (lane == 0) red[wave] = mx;
  __syncthreads();
  mx = fmaxf(fmaxf(red[0], red[1]), fmaxf(red[2], red[3]));
  float e[8], s = 0.f;
  #pragma unroll
  for (int j=0;j<8;j++){ e[j] = __expf(x[j]-mx); s += e[j]; }
  #pragma unroll
  for (int o = 32; o; o >>= 1) s += __shfl_xor(s, o, 64);
  if (lane == 0) red[4+wave] = s;
  __syncthreads();
  s = (red[4]+red[5]) + (red[6]+red[7]);
  const float inv = 1.0f / s;
  u16x8 w;
  #pragma unroll
  for (int j=0;j<8;j++) w[j] = f2h(e[j]*inv);
  reinterpret_cast<u16x8*>(p)[tid] = w;
}

// ================= fat-wave GEMM: block 256x128, 4 waves, wave tile 128x64 =================
// 24 ds_read_b128 per wave per K-step for 64 MFMA (ratio 0.375); 16x16 frag reads are
// 2-way bank aliases (free) — 32x32 is 4-way (r13 regression). Plain stores (r14:
// nontemporal amplified WRITE 65->92 MB, reverted).
// EPI=1 (PV dual): bn<8 -> C0=A@B0^T ; bn>=8 -> C1=A@B1^T + bias.
// EPI=2: fp16 out to (u16*)C0 (sim path).
template<int EPI>
__global__ __launch_bounds__(256,2) void gemmf_k(
    const u16* __restrict__ A_g, long long sAb, int lda,
    const u16* __restrict__ B0_g, const u16* __restrict__ B1_g, long long sBb, int ldb,
    float* __restrict__ C0, float* __restrict__ C1, long long sCb, int ldc,
    const float* __restrict__ bias, int K, int tn_sh){
  __shared__ __align__(16) u16 As[256*64];   // 32 KiB
  __shared__ __align__(16) u16 Bs[128*64];   // 16 KiB
  const int b = blockIdx.y;
  const int bx = xcd_swz(blockIdx.x, gridDim.x);
  const int bm = bx >> tn_sh, bn = bx & ((1 << tn_sh) - 1);
  const int tid = threadIdx.x, wave = tid>>6, lane = tid&63;
  const int wm = wave >> 1, wn = wave & 1;    // wave tile: rows wm*128, cols wn*64
  const u16* Ab = A_g + (size_t)b*sAb + (size_t)(bm*256)*lda;
  const u16* Bb;
  if (EPI == 1){
    Bb = ((bn < 8) ? B0_g : B1_g) + (size_t)b*sBb + (size_t)((bn&7)*128)*ldb;
  } else {
    Bb = B0_g + (size_t)b*sBb + (size_t)(bn*128)*ldb;
  }
  f32x4 acc[8][4];
  #pragma unroll
  for (int i=0;i<8;i++)
    #pragma unroll
    for (int j=0;j<4;j++) acc[i][j] = (f32x4){0.f,0.f,0.f,0.f};

  for (int k0 = 0; k0 < K; k0 += 64){
    __syncthreads();
    stage_fatA(As, Ab + k0, lda, wave, lane);
    stage_fatB(Bs, Bb + k0, ldb, wave, lane);
    __syncthreads();
    #pragma unroll
    for (int kk=0;kk<2;kk++){
      const int ko = kk*32 + ((lane>>4)<<3);
      f16x8 af[8], bf[4];
      #pragma unroll
      for (int mi=0;mi<8;mi++) af[mi] = frag_ld(As, wm*128 + mi*16 + (lane&15), ko);
      #pragma unroll
      for (int ni=0;ni<4;ni++) bf[ni] = frag_ld(Bs, wn*64 + ni*16 + (lane&15), ko);
      #pragma unroll
      for (int mi=0;mi<8;mi++)
        #pragma unroll
        for (int ni=0;ni<4;ni++)
          acc[mi][ni] = __builtin_amdgcn_mfma_f32_16x16x32_f16(af[mi], bf[ni], acc[mi][ni], 0,0,0);
    }
  }

  if (EPI == 2){
    u16* Oh = reinterpret_cast<u16*>(C0) + (size_t)b*sCb;
    #pragma unroll
    for (int mi=0;mi<8;mi++)
      #pragma unroll
      for (int ni=0;ni<4;ni++){
        const int r = bm*256 + wm*128 + mi*16 + ((lane>>4)<<2);
        const int c = bn*128 + wn*64 + ni*16 + (lane&15);
        #pragma unroll
        for (int j=0;j<4;j++)
          Oh[(size_t)(r+j)*ldc + c] = f2h(acc[mi][ni][j]);
      }
  } else {
    float* O = ((bn < 8) ? C0 : C1) + (size_t)b*sCb;
    const bool has_bias = (bn >= 8);
    #pragma unroll
    for (int mi=0;mi<8;mi++)
      #pragma unroll
      for (int ni=0;ni<4;ni++){
        const int r = bm*256 + wm*128 + mi*16 + ((lane>>4)<<2);
        const int c = (bn&7)*128 + wn*64 + ni*16 + (lane&15);
        const float bv = has_bias ? bias[c] : 0.f;
        #pragma unroll
        for (int j=0;j<4;j++)
          O[(size_t)(r+j)*ldc + c] = acc[mi][ni][j] + bv;
      }
  }
}

// ---------- host launch ----------
extern "C" void kernel_launch(void* const* d_in, const int* in_sizes, int n_in,
                              void* d_out, int out_size, void* d_ws, size_t ws_size,
                              hipStream_t stream) {
  const float* f1 = (const float*)d_in[0];
  const float* f2 = (const float*)d_in[1];
  const float* W1 = (const float*)d_in[2];
  const float* b1 = (const float*)d_in[3];
  const float* W2 = (const float*)d_in[4];
  const float* b2 = (const float*)d_in[5];
  float* out1 = (float*)d_out;
  float* out2 = out1 + (size_t)BB*LL*DD;

  // workspace layout (bytes); peak 100 MB + 4 KB
  char* ws = (char*)d_ws;
  u16* t1f = (u16*)(ws + 0);              // 16 MiB  fp16 t1 [b*2048][1024]
  u16* ZT  = (u16*)(ws + 16777216);       // 16 MiB  fp16 Z^T [b][1024][2048]
  u16* f2f = (u16*)(ws + 33554432);       // 16 MiB  fp16 f2
  u16* f2T = (u16*)(ws + 50331648);       // 16 MiB  fp16 f2^T
  u16* w1f = (u16*)(ws + 67108864);       // 2 MiB
  u16* w2f = (u16*)(ws + 69206016);       // 2 MiB
  u16* sim = (u16*)(ws + 71303168);       // 32 MiB fp16 [b][l][m]; attn in place
  // short-lived, alias sim region (dead before sim GEMM):
  u16* f1f  = (u16*)(ws + 71303168);                // 16 MiB
  u16* w1T  = (u16*)(ws + 71303168 + 16777216);     // 2 MiB
  u16* w12f = (u16*)(ws + 71303168 + 18874368);     // 2 MiB
  float* bz2 = (float*)(ws + 104857600);  // 4 KiB (persists through PV)

  // 1. all casts: z<4 f2 (+T); z=4 W1 (+T); z=5 flat f1/W2
  cast_all_k<<<dim3(32, 64, 6), dim3(32, 8), 0, stream>>>(f2, f2f, f2T,
                                                          W1, w1f, w1T,
                                                          f1, f1f, W2, w2f);
  // 2. bz2 = b2 + W2 @ b1 (f32, from original inputs)
  bz2_k<<<128, 512, 0, stream>>>(W2, b1, b2, bz2);
  // 3. W12 = W2 @ W1 (fp16)
  w12_k<<<64, 512, 0, stream>>>(w2f, w1T, w12f);
  // 4. fused: t1 = f1@W1^T + b1 -> t1f (bit-identical path) ; Z = f1@W12^T -> ZT
  t1z_k<<<512, 512, 0, stream>>>(f1f, w1f, w12f, b1, t1f, ZT);
  // 5. sim[b] = t1[b] @ f2[b]^T — fat-wave 16x16, fp16 out
  gemmf_k<2><<<dim3(128, BB), 256, 0, stream>>>(t1f, (long long)LL*DD, DD,
                                                f2f, nullptr, (long long)LL*DD, DD,
                                                (float*)sim, nullptr, (long long)LL*LL, LL,
                                                nullptr, DD, 4);
  // 6. softmax rows, fp16 in place
  softmax_k<<<BB*LL, 256, 0, stream>>>(sim);
  // 7. PV — fat-wave dual: bn<8 -> out1 = attn@f2 ; bn>=8 -> out2 = attn@Z + bz2
  gemmf_k<1><<<dim3(128, BB), 256, 0, stream>>>(sim, (long long)LL*LL, LL,
                                                f2T, ZT, (long long)DD*LL, LL,
                                                out1, out2, (long long)LL*DD, DD,
                                                bz2, LL, 4);
}

// Round 16
// 184.313 us; speedup vs baseline: 1.1813x; 1.1813x over previous
//
#include <hip/hip_runtime.h>
#include <stdint.h>

// Problem constants
#define BB 4
#define LL 2048
#define DD 1024

typedef __attribute__((ext_vector_type(4))) float f32x4;
typedef __attribute__((ext_vector_type(8))) _Float16 f16x8;
typedef __attribute__((ext_vector_type(4))) unsigned short u16x4;
typedef __attribute__((ext_vector_type(8))) unsigned short u16x8;
typedef unsigned short u16;

// ---------- fp16 helpers ----------
__device__ __forceinline__ u16 f2h(float x){
  return __builtin_bit_cast(u16, (_Float16)x);
}
__device__ __forceinline__ float h2f(u16 h){
  return (float)__builtin_bit_cast(_Float16, h);
}

// ---------- async global->LDS staging (16B/lane) ----------
__device__ __forceinline__ void gload16(const u16* g, u16* l){
  __builtin_amdgcn_global_load_lds((const __attribute__((address_space(1))) unsigned*)g,
                                   (__attribute__((address_space(3))) unsigned*)l,
                                   16, 0, 0);
}

// XCD-aware chunked block swizzle (requires nwg % 8 == 0; all our grids comply)
__device__ __forceinline__ int xcd_swz(int bx, int nwg){
  return (bx & 7) * (nwg >> 3) + (bx >> 3);
}

// stage a [128][64] fp16 tile, 8 waves, XOR-swizzled source, linear LDS dest
__device__ __forceinline__ void stage_tile8(u16* lds, const u16* src, int ld, int wave, int lane){
  const int r0 = lane >> 3;
  const int cs = (((lane & 7) ^ r0) << 3);
  #pragma unroll
  for (int j = 0; j < 2; ++j){
    const int rb = wave*16 + j*8;
    gload16(src + (size_t)(rb + r0)*ld + cs, lds + rb*64);
  }
}

// fat-kernel staging (4 waves / 256 threads): A [256][64], B [128][64]
__device__ __forceinline__ void stage_fatA(u16* lds, const u16* src, int ld, int wave, int lane){
  const int r0 = lane >> 3;
  const int cs = (((lane & 7) ^ r0) << 3);
  #pragma unroll
  for (int j = 0; j < 8; ++j){
    const int rb = wave*64 + j*8;
    gload16(src + (size_t)(rb + r0)*ld + cs, lds + rb*64);
  }
}
__device__ __forceinline__ void stage_fatB(u16* lds, const u16* src, int ld, int wave, int lane){
  const int r0 = lane >> 3;
  const int cs = (((lane & 7) ^ r0) << 3);
  #pragma unroll
  for (int j = 0; j < 4; ++j){
    const int rb = wave*32 + j*8;
    gload16(src + (size_t)(rb + r0)*ld + cs, lds + rb*64);
  }
}

// swizzled fragment read: logical (row, ko) lives at phys col ko ^ ((row&7)<<3)
__device__ __forceinline__ f16x8 frag_ld(const u16* t, int row, int ko){
  return __builtin_bit_cast(f16x8,
    *reinterpret_cast<const f32x4*>(t + row*64 + (ko ^ ((row & 7) << 3))));
}

// ---------- kernel: all input casts in one launch ----------
__global__ void cast_all_k(const float* __restrict__ f2, u16* __restrict__ f2f,
                           u16* __restrict__ f2T,
                           const float* __restrict__ f1, u16* __restrict__ f1f,
                           const float* __restrict__ W1, u16* __restrict__ w1f,
                           const float* __restrict__ W2, u16* __restrict__ w2f){
  __shared__ u16 t[32][33];
  const int z = blockIdx.z;
  if (z < 4){
    const int d0 = blockIdx.x*32, l0 = blockIdx.y*32;
    const float* src = f2 + (size_t)z*LL*DD;
    u16* d1 = f2f + (size_t)z*LL*DD;
    u16* d2 = f2T + (size_t)z*DD*LL;
    const int x = threadIdx.x;
    for (int j = threadIdx.y; j < 32; j += 8){
      u16 h = f2h(src[(size_t)(l0+j)*DD + d0 + x]);
      d1[(size_t)(l0+j)*DD + d0 + x] = h;
      t[j][x] = h;
    }
    __syncthreads();
    for (int j = threadIdx.y; j < 32; j += 8)
      d2[(size_t)(d0+j)*LL + l0 + x] = t[x][j];
  } else {
    const int n1 = (BB*LL*DD)/4, nw = (DD*DD)/4;
    const int ntot = n1 + 2*nw;
    const int base = (blockIdx.y*32 + blockIdx.x)*256 + threadIdx.y*32 + threadIdx.x;
    const int stride = 2048*256;
    for (int i = base; i < ntot; i += stride){
      const float* s; u16* d; int k;
      if (i < n1){ s = f1; d = f1f; k = i; }
      else if (i < n1 + nw){ s = W1; d = w1f; k = i - n1; }
      else { s = W2; d = w2f; k = i - n1 - nw; }
      f32x4 v = reinterpret_cast<const f32x4*>(s)[k];
      u16x4 h;
      #pragma unroll
      for (int j = 0; j < 4; ++j) h[j] = f2h(v[j]);
      reinterpret_cast<u16x4*>(d)[k] = h;
    }
  }
}

// ---------- fp16 GEMM 128x128 (t1), 8 waves ----------
__global__ __launch_bounds__(512,4) void gemm_t1_k(
    const u16* __restrict__ A_g, const u16* __restrict__ B_g,
    const float* __restrict__ bias, u16* __restrict__ Oh){
  __shared__ __align__(16) u16 As[128*64];
  __shared__ __align__(16) u16 Bs[128*64];
  const int bx = xcd_swz(blockIdx.x, gridDim.x);
  const int bm = bx >> 3, bn = bx & 7;
  const int tid = threadIdx.x, wave = tid>>6, lane = tid&63;
  const int wr = wave>>2, wc = wave&3;
  const u16* Ab = A_g + (size_t)(bm*128)*DD;
  const u16* Bb = B_g + (size_t)(bn*128)*DD;
  f32x4 acc[4][2];
  #pragma unroll
  for (int i=0;i<4;i++)
    #pragma unroll
    for (int j=0;j<2;j++) acc[i][j] = (f32x4){0.f,0.f,0.f,0.f};

  for (int k0 = 0; k0 < DD; k0 += 64){
    __syncthreads();
    stage_tile8(As, Ab + k0, DD, wave, lane);
    stage_tile8(Bs, Bb + k0, DD, wave, lane);
    __syncthreads();
    #pragma unroll
    for (int kk=0;kk<2;kk++){
      const int ko = kk*32 + ((lane>>4)<<3);
      f16x8 a[4], bb[2];
      #pragma unroll
      for (int mi=0;mi<4;mi++) a[mi]  = frag_ld(As, wr*64 + mi*16 + (lane&15), ko);
      #pragma unroll
      for (int ni=0;ni<2;ni++) bb[ni] = frag_ld(Bs, wc*32 + ni*16 + (lane&15), ko);
      #pragma unroll
      for (int mi=0;mi<4;mi++)
        #pragma unroll
        for (int ni=0;ni<2;ni++)
          acc[mi][ni] = __builtin_amdgcn_mfma_f32_16x16x32_f16(a[mi], bb[ni], acc[mi][ni], 0,0,0);
    }
  }
  #pragma unroll
  for (int mi=0;mi<4;mi++)
    #pragma unroll
    for (int ni=0;ni<2;ni++){
      const int r = bm*128 + wr*64 + mi*16 + ((lane>>4)<<2);
      const int c = bn*128 + wc*32 + ni*16 + (lane&15);
      const float bv = bias[c];
      #pragma unroll
      for (int j=0;j<4;j++)
        Oh[(size_t)(r+j)*DD + c] = f2h(acc[mi][ni][j] + bv);
    }
}

// ---------- kernel: ZT = (t1 @ W2^T)^T fp16, 128-tile, LDS-staged coalesced out ----------
__global__ __launch_bounds__(512,4) void gemm_zt_k(const u16* __restrict__ t1f,
                                                   const u16* __restrict__ w2f,
                                                   u16* __restrict__ ZT){
  __shared__ __align__(16) u16 As[128*64];
  __shared__ __align__(16) u16 Bs[128*64];
  __shared__ u16 T[128*132];
  const int bx = xcd_swz(blockIdx.x, gridDim.x);
  const int bm = bx >> 3, bn = bx & 7;
  const int tid = threadIdx.x, wave = tid>>6, lane = tid&63;
  const int wr = wave>>2, wc = wave&3;
  const u16* Ab = t1f + (size_t)(bm*128)*DD;
  const u16* Bb = w2f + (size_t)(bn*128)*DD;
  f32x4 acc[4][2];
  #pragma unroll
  for (int i=0;i<4;i++)
    #pragma unroll
    for (int j=0;j<2;j++) acc[i][j] = (f32x4){0.f,0.f,0.f,0.f};

  for (int k0 = 0; k0 < DD; k0 += 64){
    __syncthreads();
    stage_tile8(As, Ab + k0, DD, wave, lane);
    stage_tile8(Bs, Bb + k0, DD, wave, lane);
    __syncthreads();
    #pragma unroll
    for (int kk=0;kk<2;kk++){
      const int ko = kk*32 + ((lane>>4)<<3);
      f16x8 a[4], bb[2];
      #pragma unroll
      for (int mi=0;mi<4;mi++) a[mi]  = frag_ld(As, wr*64 + mi*16 + (lane&15), ko);
      #pragma unroll
      for (int ni=0;ni<2;ni++) bb[ni] = frag_ld(Bs, wc*32 + ni*16 + (lane&15), ko);
      #pragma unroll
      for (int mi=0;mi<4;mi++)
        #pragma unroll
        for (int ni=0;ni<2;ni++)
          acc[mi][ni] = __builtin_amdgcn_mfma_f32_16x16x32_f16(a[mi], bb[ni], acc[mi][ni], 0,0,0);
    }
  }
  #pragma unroll
  for (int mi=0;mi<4;mi++)
    #pragma unroll
    for (int ni=0;ni<2;ni++){
      const int r = wr*64 + mi*16 + ((lane>>4)<<2);
      const int c = wc*32 + ni*16 + (lane&15);
      #pragma unroll
      for (int j=0;j<4;j++)
        T[(r+j)*132 + c] = f2h(acc[mi][ni][j]);
    }
  __syncthreads();
  const int b2i = bm >> 4;
  const int mb  = (bm*128) & 2047;
  const int d   = tid >> 2, m0 = (tid & 3) << 5;
  u16* dst = ZT + ((size_t)b2i*DD + bn*128 + d)*LL + mb + m0;
  #pragma unroll
  for (int g = 0; g < 4; ++g){
    u16x8 v;
    #pragma unroll
    for (int e = 0; e < 8; ++e) v[e] = T[(m0 + g*8 + e)*132 + d];
    *reinterpret_cast<u16x8*>(dst + g*8) = v;
  }
}

// ---------- kernel: row softmax fp16 -> fp16 in place ----------
__global__ __launch_bounds__(256) void softmax_k(u16* __restrict__ sim){
  const int row = blockIdx.x;
  u16* p = sim + (size_t)row * LL;
  const int tid = threadIdx.x, wave = tid>>6, lane = tid&63;
  u16x8 v = reinterpret_cast<const u16x8*>(p)[tid];
  float x[8];
  #pragma unroll
  for (int j=0;j<8;j++) x[j] = h2f(v[j]);
  float mx = fmaxf(fmaxf(fmaxf(x[0],x[1]), fmaxf(x[2],x[3])),
                   fmaxf(fmaxf(x[4],x[5]), fmaxf(x[6],x[7])));
  #pragma unroll
  for (int o = 32; o; o >>= 1) mx = fmaxf(mx, __shfl_xor(mx, o, 64));
  __shared__ float red[8];
  if (lane == 0) red[wave] = mx;
  __syncthreads();
  mx = fmaxf(fmaxf(red[0], red[1]), fmaxf(red[2], red[3]));
  float e[8], s = 0.f;
  #pragma unroll
  for (int j=0;j<8;j++){ e[j] = __expf(x[j]-mx); s += e[j]; }
  #pragma unroll
  for (int o = 32; o; o >>= 1) s += __shfl_xor(s, o, 64);
  if (lane == 0) red[4+wave] = s;
  __syncthreads();
  s = (red[4]+red[5]) + (red[6]+red[7]);
  const float inv = 1.0f / s;
  u16x8 w;
  #pragma unroll
  for (int j=0;j<8;j++) w[j] = f2h(e[j]*inv);
  reinterpret_cast<u16x8*>(p)[tid] = w;
}

// ================= fat-wave GEMM: block 256x128, 4 waves, wave tile 128x64 =================
// 24 ds_read_b128 per wave per K-step for 64 MFMA (ratio 0.375).
// __launch_bounds__(256,2): VGPR cap 256 — acc(128) + frags(48) + addr fits, NO SPILL.
// EPI=1 (PV dual): bn<8 -> C0=A@B0^T ; bn>=8 -> C1=A@B1^T + bias.
// EPI=2: fp16 out to (u16*)C0 (sim path).
template<int EPI>
__global__ __launch_bounds__(256,2) void gemmf_k(
    const u16* __restrict__ A_g, long long sAb, int lda,
    const u16* __restrict__ B0_g, const u16* __restrict__ B1_g, long long sBb, int ldb,
    float* __restrict__ C0, float* __restrict__ C1, long long sCb, int ldc,
    const float* __restrict__ bias, int K, int tn_sh){
  __shared__ __align__(16) u16 As[256*64];   // 32 KiB
  __shared__ __align__(16) u16 Bs[128*64];   // 16 KiB
  const int b = blockIdx.y;
  const int bx = xcd_swz(blockIdx.x, gridDim.x);
  const int bm = bx >> tn_sh, bn = bx & ((1 << tn_sh) - 1);
  const int tid = threadIdx.x, wave = tid>>6, lane = tid&63;
  const int wm = wave >> 1, wn = wave & 1;    // wave tile: rows wm*128, cols wn*64
  const u16* Ab = A_g + (size_t)b*sAb + (size_t)(bm*256)*lda;
  const u16* Bb;
  if (EPI == 1){
    Bb = ((bn < 8) ? B0_g : B1_g) + (size_t)b*sBb + (size_t)((bn&7)*128)*ldb;
  } else {
    Bb = B0_g + (size_t)b*sBb + (size_t)(bn*128)*ldb;
  }
  f32x4 acc[8][4];
  #pragma unroll
  for (int i=0;i<8;i++)
    #pragma unroll
    for (int j=0;j<4;j++) acc[i][j] = (f32x4){0.f,0.f,0.f,0.f};

  for (int k0 = 0; k0 < K; k0 += 64){
    __syncthreads();
    stage_fatA(As, Ab + k0, lda, wave, lane);
    stage_fatB(Bs, Bb + k0, ldb, wave, lane);
    __syncthreads();
    #pragma unroll
    for (int kk=0;kk<2;kk++){
      const int ko = kk*32 + ((lane>>4)<<3);
      f16x8 af[8], bf[4];
      #pragma unroll
      for (int mi=0;mi<8;mi++) af[mi] = frag_ld(As, wm*128 + mi*16 + (lane&15), ko);
      #pragma unroll
      for (int ni=0;ni<4;ni++) bf[ni] = frag_ld(Bs, wn*64 + ni*16 + (lane&15), ko);
      #pragma unroll
      for (int mi=0;mi<8;mi++)
        #pragma unroll
        for (int ni=0;ni<4;ni++)
          acc[mi][ni] = __builtin_amdgcn_mfma_f32_16x16x32_f16(af[mi], bf[ni], acc[mi][ni], 0,0,0);
    }
  }

  if (EPI == 2){
    u16* Oh = reinterpret_cast<u16*>(C0) + (size_t)b*sCb;
    #pragma unroll
    for (int mi=0;mi<8;mi++)
      #pragma unroll
      for (int ni=0;ni<4;ni++){
        const int r = bm*256 + wm*128 + mi*16 + ((lane>>4)<<2);
        const int c = bn*128 + wn*64 + ni*16 + (lane&15);
        #pragma unroll
        for (int j=0;j<4;j++)
          Oh[(size_t)(r+j)*ldc + c] = f2h(acc[mi][ni][j]);
      }
  } else {
    float* O = ((bn < 8) ? C0 : C1) + (size_t)b*sCb;
    const bool has_bias = (bn >= 8);
    #pragma unroll
    for (int mi=0;mi<8;mi++)
      #pragma unroll
      for (int ni=0;ni<4;ni++){
        const int r = bm*256 + wm*128 + mi*16 + ((lane>>4)<<2);
        const int c = (bn&7)*128 + wn*64 + ni*16 + (lane&15);
        const float bv = has_bias ? bias[c] : 0.f;
        #pragma unroll
        for (int j=0;j<4;j++)
          O[(size_t)(r+j)*ldc + c] = acc[mi][ni][j] + bv;
      }
  }
}

// ---------- host launch ----------
extern "C" void kernel_launch(void* const* d_in, const int* in_sizes, int n_in,
                              void* d_out, int out_size, void* d_ws, size_t ws_size,
                              hipStream_t stream) {
  const float* f1 = (const float*)d_in[0];
  const float* f2 = (const float*)d_in[1];
  const float* W1 = (const float*)d_in[2];
  const float* b1 = (const float*)d_in[3];
  const float* W2 = (const float*)d_in[4];
  const float* b2 = (const float*)d_in[5];
  float* out1 = (float*)d_out;
  float* out2 = out1 + (size_t)BB*LL*DD;

  // workspace layout (bytes); peak 104 MB
  char* ws = (char*)d_ws;
  u16* t1f = (u16*)(ws + 0);              // 16 MiB  fp16 t1 [b*2048][1024]
  u16* ZT  = (u16*)(ws + 16777216);       // 16 MiB  fp16 Z^T [b][1024][2048]
  u16* f2f = (u16*)(ws + 33554432);       // 16 MiB  fp16 f2
  u16* f2T = (u16*)(ws + 50331648);       // 16 MiB  fp16 f2^T
  u16* w1f = (u16*)(ws + 67108864);       // 2 MiB
  u16* w2f = (u16*)(ws + 69206016);       // 2 MiB
  u16* sim = (u16*)(ws + 71303168);       // 32 MiB fp16 [b][l][m]; attn in place
  u16* f1f = (u16*)(ws + 71303168);       // 16 MiB, aliases sim (dead before sim GEMM)

  // 1. all casts in one launch: z<4 f2 (cast+transpose), z=4 flat f1/W1/W2
  cast_all_k<<<dim3(32, 64, 5), dim3(32, 8), 0, stream>>>(f2, f2f, f2T,
                                                          f1, f1f, W1, w1f, W2, w2f);
  // 2. t1 = f1 @ W1^T + b1 (fp16), 128-tile
  gemm_t1_k<<<dim3(512, 1), 512, 0, stream>>>(f1f, w1f, b1, t1f);
  // 3. sim[b] = t1[b] @ f2[b]^T — fat-wave 16x16, fp16 out (bit-identical attn path)
  gemmf_k<2><<<dim3(128, BB), 256, 0, stream>>>(t1f, (long long)LL*DD, DD,
                                                f2f, nullptr, (long long)LL*DD, DD,
                                                (float*)sim, nullptr, (long long)LL*LL, LL,
                                                nullptr, DD, 4);
  // 4. softmax rows, fp16 in place (contiguous 2048-elem rows)
  softmax_k<<<BB*LL, 256, 0, stream>>>(sim);
  // 5. ZT = (t1 @ W2^T)^T fp16 (coalesced epilogue)
  gemm_zt_k<<<dim3(512, 1), 512, 0, stream>>>(t1f, w2f, ZT);
  // 6. PV — fat-wave 16x16 dual: bn<8 -> out1 = attn@f2 ; bn>=8 -> out2 = attn@Z + b2
  gemmf_k<1><<<dim3(128, BB), 256, 0, stream>>>(sim, (long long)LL*LL, LL,
                                                f2T, ZT, (long long)DD*LL, LL,
                                                out1, out2, (long long)LL*DD, DD,
                                                b2, LL, 4);
}